// Round 4
// baseline (3168.053 us; speedup 1.0000x reference)
//
#include <hip/hip_runtime.h>
#include <cstdint>

// WeatherSTGNN persistent kernel, round 4.
// 1 batch per block, grid 2048 x 512 threads (8 waves), 2 blocks/CU
// (LDS ~56KB, launch_bounds(512,4) -> 128 VGPR cap). W_ih|W_hh B-fragments
// live in 32 persistent VGPRs per wave (each wave uses only its own 32-col
// slice); Ahat hi/lo split in 16 VGPRs (exact to ~2^-16). All big GEMMs on
// MFMA bf16 32x32x16 with C written directly into the next op's fragment
// layout (round-3 pass-verified conventions). dec1+dec2 fused on one wave
// (dec2 via MFMA against zero-padded Wd2 B-frag; wave-internal LDS dep ->
// no barrier). Per-step barriers: 7 (enc) / 8 (dec); the co-resident second
// block hides barrier-drain latency.

#define NT 512
#define TSTEPS 48
#define FUT 48

typedef __bf16 bf16;
typedef __attribute__((ext_vector_type(4))) __bf16 bf16x4;
typedef __attribute__((ext_vector_type(8))) __bf16 bf16x8;
typedef __attribute__((ext_vector_type(16))) float f32x16;

__device__ __forceinline__ float sigm(float x) { return 1.0f / (1.0f + __expf(-x)); }
__device__ __forceinline__ float tanh_fast(float x) { return 1.0f - 2.0f / (__expf(2.0f * x) + 1.0f); }

__global__ __launch_bounds__(NT, 4)
void stgnn_kernel(const float* __restrict__ xh, const float* __restrict__ adj,
                  const float* __restrict__ Wenc, const float* __restrict__ benc,
                  const float* __restrict__ Wg1, const float* __restrict__ bg1,
                  const float* __restrict__ Wg2, const float* __restrict__ bg2,
                  const float* __restrict__ Wih, const float* __restrict__ Whh,
                  const float* __restrict__ bih, const float* __restrict__ bhh,
                  const float* __restrict__ Wd1, const float* __restrict__ bd1,
                  const float* __restrict__ Wd2, const float* __restrict__ bd2,
                  float* __restrict__ out) {
  // ---- LDS (~56KB total) ----
  __shared__ __align__(16) char  sPool[16896];   // encF/t1F/s1F/t2F (+) sGb (+) d1A (+) AhatS
  __shared__ __align__(16) bf16  xfhF[4096];     // [xf k0..63 | h k64..127] A-frag (8KB)
  __shared__ __align__(16) bf16  wg1F[4096];     // Wg1 B-frag Kc=4,N=64 (8KB)
  __shared__ __align__(16) bf16  wg2F[4096];     // Wg2^T A-frag, 2 M-tiles (8KB)
  __shared__ __align__(16) bf16  wd1F[2048];     // Wd1 B-frag Kc=4,N=32 (4KB)
  __shared__ __align__(16) bf16  wd2F[1024];     // Wd2 B-frag Kc=2,N=32 zero-padded (2KB)
  __shared__ __align__(16) float sWenc[704];
  __shared__ __align__(16) float sX[2][384];
  __shared__ __align__(16) float sBenc[64];
  __shared__ __align__(16) float sBg1[64];
  __shared__ __align__(16) float sBg2[64];
  __shared__ __align__(16) float sBih[256];
  __shared__ __align__(16) float sBd1[32];
  __shared__ __align__(16) float sBd2[8];
  __shared__ float sDeg[32];

  const int tid  = threadIdx.x;
  const int lane = tid & 63;
  const int wv   = tid >> 6;        // wave 0..7
  const int r    = tid >> 4;        // node row 0..31
  const int hb   = (tid & 15) << 2; // h base 0,4,...,60
  const int hf4  = (lane >> 5) * 4;
  const long long b = blockIdx.x;

  bf16* encF = (bf16*)(sPool + 0);
  bf16* t1F  = (bf16*)(sPool + 4096);
  bf16* s1F  = (bf16*)(sPool + 8192);
  bf16* t2F  = (bf16*)(sPool + 12288);
  bf16* sGb  = (bf16*)(sPool);          // 32 x 264 bf16 (16.5KB)
  bf16* d1A  = (bf16*)(sPool);          // 2048 bf16 (4KB), decoder only

  // ---------------- stage static LDS ----------------
  for (int i = tid; i < 704; i += NT) sWenc[i] = Wenc[i];
  for (int i = tid; i < 64; i += NT) { sBenc[i] = benc[i]; sBg1[i] = bg1[i]; sBg2[i] = bg2[i]; }
  for (int i = tid; i < 256; i += NT) sBih[i] = bih[i] + bhh[i];
  for (int i = tid; i < 32; i += NT) sBd1[i] = bd1[i];
  if (tid < 8) sBd2[tid] = (tid < 6) ? bd2[tid] : 0.0f;
  for (int i = tid; i < 4096; i += NT) {
    int k = i >> 6, n = i & 63;
    wg1F[((((n >> 5) * 4 + (k >> 4)) * 64) + (n & 31) + 32 * ((k >> 3) & 1)) * 8 + (k & 7)] = (bf16)Wg1[i];
    int m = n;  // Wg2^T A-frag: element Wg2[k(h1)][m(h2)], tile m>>5
    wg2F[(m >> 5) * 2048 + (((k >> 4) * 64) + (m & 31) + 32 * ((k >> 3) & 1)) * 8 + (k & 7)] = (bf16)Wg2[k * 64 + m];
  }
  for (int i = tid; i < 2048; i += NT) {
    int k = i >> 5, n = i & 31;
    wd1F[(((k >> 4) * 64) + n + 32 * ((k >> 3) & 1)) * 8 + (k & 7)] = (bf16)Wd1[i];
  }
  for (int i = tid; i < 1024; i += NT) {
    int k = i >> 5, n = i & 31;
    float v = (n < 6) ? Wd2[k * 6 + n] : 0.0f;
    wd2F[(((k >> 4) * 64) + n + 32 * ((k >> 3) & 1)) * 8 + (k & 7)] = (bf16)v;
  }
  if (tid < 32) {
    float s = 0.0f;
    for (int j = 0; j < 32; ++j) s += (j == tid) ? 1.0f : adj[tid * 32 + j];
    sDeg[tid] = 1.0f / sqrtf(fmaxf(s, 1.0f));
  }
  // W_ih|W_hh B-fragments -> 32 persistent VGPRs per wave (slice cols wv*32..+31)
  bf16x8 wcatR[8];
  {
    const int col = wv * 32 + (lane & 31);
    #pragma unroll
    for (int c = 0; c < 8; ++c) {
      const float* src = (c < 4) ? (Wih + col * 64 + 16 * c + 8 * (lane >> 5))
                                 : (Whh + col * 64 + 16 * (c - 4) + 8 * (lane >> 5));
      float4 lo = *reinterpret_cast<const float4*>(src);
      float4 hi = *reinterpret_cast<const float4*>(src + 4);
      bf16x8 w = { (bf16)lo.x, (bf16)lo.y, (bf16)lo.z, (bf16)lo.w,
                   (bf16)hi.x, (bf16)hi.y, (bf16)hi.z, (bf16)hi.w };
      wcatR[c] = w;
    }
  }
  __syncthreads();
  // Ahat fp32 scratch in pool
  float* AhatS = (float*)(sPool);
  for (int i = tid; i < 1024; i += NT) {
    int ii = i >> 5, jj = i & 31;
    float v = (ii == jj) ? 1.0f : adj[i];
    AhatS[i] = sDeg[ii] * v * sDeg[jj];
  }
  __syncthreads();
  // Ahat hi/lo fragments (same lane map serves A and B=Ahat^T orientations)
  bf16x8 ahHi[2], ahLo[2];
  #pragma unroll
  for (int c = 0; c < 2; ++c)
    #pragma unroll
    for (int j = 0; j < 8; ++j) {
      int k = 16 * c + 8 * (lane >> 5) + j;
      float v = AhatS[(lane & 31) * 32 + k];
      bf16 hi = (bf16)v;
      ahHi[c][j] = hi;
      ahLo[c][j] = (bf16)(v - (float)hi);
    }
  // zero h-half of xfh (h(0)=0); load x step 0
  for (int i = tid; i < 2048; i += NT) xfhF[2048 + i] = (bf16)0.0f;
  if (tid < 352) {
    int j = tid / 11, f = tid - j * 11;
    sX[0][j * 12 + f] = xh[((b * TSTEPS + 0) * 32 + j) * 11 + f];
  }
  float cx[4] = {0.0f, 0.0f, 0.0f, 0.0f};
  __syncthreads();

  for (int step = 0; step < TSTEPS + FUT; ++step) {
    const bool de = (step >= TSTEPS);
    const int  sb = step & 1;
    float* sXc = de ? sX[1] : sX[sb];
    // ---- ph2 (VALU, all): enc = relu(x @ Wenc + benc) -> encF A-frag; x prefetch
    {
      float4 acc = *reinterpret_cast<const float4*>(&sBenc[hb]);
      #pragma unroll
      for (int k = 0; k < 11; ++k) {
        float x = sXc[r * 12 + k];
        float4 w = *reinterpret_cast<const float4*>(&sWenc[k * 64 + hb]);
        acc.x += x * w.x; acc.y += x * w.y; acc.z += x * w.z; acc.w += x * w.w;
      }
      bf16x4 o = { (bf16)fmaxf(acc.x, 0.f), (bf16)fmaxf(acc.y, 0.f),
                   (bf16)fmaxf(acc.z, 0.f), (bf16)fmaxf(acc.w, 0.f) };
      *reinterpret_cast<bf16x4*>(&encF[(((hb >> 4) * 64) + r + 32 * ((hb >> 3) & 1)) * 8 + (hb & 7)]) = o;
      if (!de && step < TSTEPS - 1 && tid < 352) {
        int j = tid / 11, f = tid - j * 11;
        sX[sb ^ 1][j * 12 + f] = xh[((b * TSTEPS + step + 1) * 32 + j) * 11 + f];
      }
    }
    __syncthreads();  // B1
    // ---- T1 (MFMA, waves 0-1): t1 = enc @ Wg1 -> t1F (t1^T A-frag, b64)
    if (wv < 2) {
      f32x16 c;
      #pragma unroll
      for (int i = 0; i < 16; ++i) c[i] = 0.0f;
      #pragma unroll
      for (int ch = 0; ch < 4; ++ch) {
        bf16x8 a  = *reinterpret_cast<const bf16x8*>(&encF[(ch * 64 + lane) * 8]);
        bf16x8 bv = *reinterpret_cast<const bf16x8*>(&wg1F[((wv * 4 + ch) * 64 + lane) * 8]);
        c = __builtin_amdgcn_mfma_f32_32x32x16_bf16(a, bv, c, 0, 0, 0);
      }
      #pragma unroll
      for (int g = 0; g < 4; ++g) {
        bf16x4 o = { (bf16)c[4*g], (bf16)c[4*g+1], (bf16)c[4*g+2], (bf16)c[4*g+3] };
        *reinterpret_cast<bf16x4*>(&t1F[wv * 2048 + (((g >> 1) * 64) + (lane & 31) + 32 * (g & 1)) * 8 + hf4]) = o;
      }
    }
    __syncthreads();  // B2
    // ---- S1 (MFMA, waves 0-1): s1^T = t1^T @ Ahat^T (hi+lo) +bg1, relu -> s1F B-frag
    if (wv < 2) {
      f32x16 c;
      #pragma unroll
      for (int i = 0; i < 16; ++i) c[i] = 0.0f;
      #pragma unroll
      for (int ch = 0; ch < 2; ++ch) {
        bf16x8 a = *reinterpret_cast<const bf16x8*>(&t1F[wv * 2048 + (ch * 64 + lane) * 8]);
        c = __builtin_amdgcn_mfma_f32_32x32x16_bf16(a, ahHi[ch], c, 0, 0, 0);
        c = __builtin_amdgcn_mfma_f32_32x32x16_bf16(a, ahLo[ch], c, 0, 0, 0);
      }
      #pragma unroll
      for (int g = 0; g < 4; ++g) {
        bf16 p[4];
        #pragma unroll
        for (int i = 0; i < 4; ++i) {
          int h1 = 32 * wv + 8 * g + hf4 + i;
          p[i] = (bf16)fmaxf(c[4*g+i] + sBg1[h1], 0.f);
        }
        bf16x4 o = { p[0], p[1], p[2], p[3] };
        *reinterpret_cast<bf16x4*>(&s1F[(((2 * wv + (g >> 1)) * 64) + (lane & 31) + 32 * (g & 1)) * 8 + hf4]) = o;
      }
    }
    __syncthreads();  // B3
    // ---- T2 (MFMA, waves 0-1): t2^T = Wg2^T @ s1^T -> t2F (XF B-frag, b16 scatter)
    if (wv < 2) {
      f32x16 c;
      #pragma unroll
      for (int i = 0; i < 16; ++i) c[i] = 0.0f;
      #pragma unroll
      for (int ch = 0; ch < 4; ++ch) {
        bf16x8 a  = *reinterpret_cast<const bf16x8*>(&wg2F[wv * 2048 + (ch * 64 + lane) * 8]);
        bf16x8 bv = *reinterpret_cast<const bf16x8*>(&s1F[(ch * 64 + lane) * 8]);
        c = __builtin_amdgcn_mfma_f32_32x32x16_bf16(a, bv, c, 0, 0, 0);
      }
      const int node = lane & 31;
      const int sbase = ((wv * 2 + (node >> 4)) * 64 + 32 * ((node >> 3) & 1)) * 8 + (node & 7);
      #pragma unroll
      for (int ri = 0; ri < 16; ++ri) {
        int rl = (ri & 3) + 8 * (ri >> 2) + hf4;
        t2F[sbase + rl * 8] = (bf16)c[ri];
      }
    }
    __syncthreads();  // B4
    // ---- XF (MFMA, waves 0-1): xf = Ahat @ t2 (hi+lo) +bg2, relu -> xfhF k<64
    if (wv < 2) {
      f32x16 c;
      #pragma unroll
      for (int i = 0; i < 16; ++i) c[i] = 0.0f;
      #pragma unroll
      for (int ch = 0; ch < 2; ++ch) {
        bf16x8 bv = *reinterpret_cast<const bf16x8*>(&t2F[((wv * 2 + ch) * 64 + lane) * 8]);
        c = __builtin_amdgcn_mfma_f32_32x32x16_bf16(ahHi[ch], bv, c, 0, 0, 0);
        c = __builtin_amdgcn_mfma_f32_32x32x16_bf16(ahLo[ch], bv, c, 0, 0, 0);
      }
      const int h2 = 32 * wv + (lane & 31);
      const float bias = sBg2[h2];
      const int abase = (((h2 >> 4) * 64) + 32 * ((h2 >> 3) & 1)) * 8 + (h2 & 7);
      #pragma unroll
      for (int ri = 0; ri < 16; ++ri) {
        int node = (ri & 3) + 8 * (ri >> 2) + hf4;
        xfhF[abase + node * 8] = (bf16)fmaxf(c[ri] + bias, 0.f);
      }
    }
    __syncthreads();  // B5
    // ---- LSTM (MFMA, all 8 waves): g = [xf|h] @ Wcat (B from regs) -> sGb bf16
    {
      f32x16 c;
      #pragma unroll
      for (int i = 0; i < 16; ++i) c[i] = 0.0f;
      #pragma unroll
      for (int ch = 0; ch < 8; ++ch) {
        bf16x8 a = *reinterpret_cast<const bf16x8*>(&xfhF[(ch * 64 + lane) * 8]);
        c = __builtin_amdgcn_mfma_f32_32x32x16_bf16(a, wcatR[ch], c, 0, 0, 0);
      }
      const int col = wv * 32 + (lane & 31);
      #pragma unroll
      for (int ri = 0; ri < 16; ++ri) {
        int node = (ri & 3) + 8 * (ri >> 2) + hf4;
        sGb[node * 264 + col] = (bf16)c[ri];
      }
    }
    __syncthreads();  // B6
    // ---- nonlin (VALU, all): gates -> c,h ; h -> xfhF k>=64 (b64)
    {
      float g4[4][4];
      #pragma unroll
      for (int gi = 0; gi < 4; ++gi) {
        bf16x4 gv = *reinterpret_cast<const bf16x4*>(&sGb[r * 264 + gi * 64 + hb]);
        float4 bi = *reinterpret_cast<const float4*>(&sBih[gi * 64 + hb]);
        g4[gi][0] = (float)gv[0] + bi.x; g4[gi][1] = (float)gv[1] + bi.y;
        g4[gi][2] = (float)gv[2] + bi.z; g4[gi][3] = (float)gv[3] + bi.w;
      }
      bf16 hp[4];
      #pragma unroll
      for (int i = 0; i < 4; ++i) {
        float cc = sigm(g4[1][i]) * cx[i] + sigm(g4[0][i]) * tanh_fast(g4[2][i]);
        cx[i] = cc;
        hp[i] = (bf16)(sigm(g4[3][i]) * tanh_fast(cc));
      }
      bf16x4 hv = { hp[0], hp[1], hp[2], hp[3] };
      *reinterpret_cast<bf16x4*>(&xfhF[(((4 + (hb >> 4)) * 64) + r + 32 * ((hb >> 3) & 1)) * 8 + (hb & 7)]) = hv;
    }
    __syncthreads();  // B7
    // ---- decoder: dec1+dec2 fused on wave 4 (wave-internal LDS dep, no barrier)
    if (de) {
      if (wv == 4) {
        f32x16 c;
        #pragma unroll
        for (int i = 0; i < 16; ++i) c[i] = 0.0f;
        #pragma unroll
        for (int ch = 0; ch < 4; ++ch) {
          bf16x8 a  = *reinterpret_cast<const bf16x8*>(&xfhF[((4 + ch) * 64 + lane) * 8]);
          bf16x8 bv = *reinterpret_cast<const bf16x8*>(&wd1F[(ch * 64 + lane) * 8]);
          c = __builtin_amdgcn_mfma_f32_32x32x16_bf16(a, bv, c, 0, 0, 0);
        }
        const int col = lane & 31;
        const float bb = sBd1[col];
        const int abase = ((col >> 4) * 64 + 32 * ((col >> 3) & 1)) * 8 + (col & 7);
        #pragma unroll
        for (int ri = 0; ri < 16; ++ri) {
          int node = (ri & 3) + 8 * (ri >> 2) + hf4;
          d1A[abase + node * 8] = (bf16)fmaxf(c[ri] + bb, 0.f);
        }
        // dec2: res = d1 @ Wd2 (+bd2); pred += res; store
        f32x16 c2;
        #pragma unroll
        for (int i = 0; i < 16; ++i) c2[i] = 0.0f;
        #pragma unroll
        for (int ch = 0; ch < 2; ++ch) {
          bf16x8 a  = *reinterpret_cast<const bf16x8*>(&d1A[(ch * 64 + lane) * 8]);
          bf16x8 bv = *reinterpret_cast<const bf16x8*>(&wd2F[(ch * 64 + lane) * 8]);
          c2 = __builtin_amdgcn_mfma_f32_32x32x16_bf16(a, bv, c2, 0, 0, 0);
        }
        const int d = lane & 31;
        if (d < 6) {
          const float bb2 = sBd2[d];
          #pragma unroll
          for (int ri = 0; ri < 16; ++ri) {
            int node = (ri & 3) + 8 * (ri >> 2) + hf4;
            float p = sXc[node * 12 + d] + c2[ri] + bb2;
            sXc[node * 12 + d] = p;
            out[((b * FUT + (step - TSTEPS)) * 32 + node) * 6 + d] = p;
          }
        }
      }
      __syncthreads();  // B8
    }
  }
}

extern "C" void kernel_launch(void* const* d_in, const int* in_sizes, int n_in,
                              void* d_out, int out_size, void* d_ws, size_t ws_size,
                              hipStream_t stream) {
  (void)in_sizes; (void)n_in; (void)d_ws; (void)ws_size; (void)out_size;
  const float* xh   = (const float*)d_in[0];
  const float* adj  = (const float*)d_in[1];
  const float* Wenc = (const float*)d_in[2];
  const float* benc = (const float*)d_in[3];
  const float* Wg1  = (const float*)d_in[4];
  const float* bg1  = (const float*)d_in[5];
  const float* Wg2  = (const float*)d_in[6];
  const float* bg2  = (const float*)d_in[7];
  const float* Wih  = (const float*)d_in[8];
  const float* Whh  = (const float*)d_in[9];
  const float* bih  = (const float*)d_in[10];
  const float* bhh  = (const float*)d_in[11];
  const float* Wd1  = (const float*)d_in[12];
  const float* bd1  = (const float*)d_in[13];
  const float* Wd2  = (const float*)d_in[14];
  const float* bd2  = (const float*)d_in[15];
  float* out = (float*)d_out;
  stgnn_kernel<<<dim3(2048), dim3(NT), 0, stream>>>(
      xh, adj, Wenc, benc, Wg1, bg1, Wg2, bg2,
      Wih, Whh, bih, bhh, Wd1, bd1, Wd2, bd2, out);
}

// Round 5
// 1572.090 us; speedup vs baseline: 2.0152x; 2.0152x over previous
//
#include <hip/hip_runtime.h>
#include <cstdint>

// WeatherSTGNN persistent kernel, round 5: one wave = one batch, ZERO barriers
// in the 96-step loop. Grid 256 x 512 (8 waves/block, 1 block/CU, one round).
// GEMM chain alternates orientation (enc^T, t1, s1^T, t2, xf^T, g^T, d1^T, d2^T)
// so every C->next-operand transform is contraction-dim==C-rows => packed
// ds_write_b64 into a private 4KB chain buffer (wave-internal in-order LDS, no
// sync). Ahat^T hi/lo in 16 VGPRs serves both mixes as B (exact to ~2^-16).
// [xf|h]^T B-frags + cell state + pred live in registers. Fragment maps are
// the R2-R4 pass-verified ones: A-frag ((mt*Kc+c)*64+lane)*8 lane=m+32*((k>>3)&1),
// k&7 elem; B-frag ((nt*Kc+c)*64+lane)*8 lane=(n&31)+32*((k>>3)&1);
// C col=lane&31, row=(r&3)+8*(r>>2)+4*(lane>>5).

#define NT 512
#define TSTEPS 48
#define FUT 48

typedef __bf16 bf16;
typedef __attribute__((ext_vector_type(4))) __bf16 bf16x4;
typedef __attribute__((ext_vector_type(8))) __bf16 bf16x8;
typedef __attribute__((ext_vector_type(16))) float f32x16;

__device__ __forceinline__ float sigm(float x) { return 1.0f / (1.0f + __expf(-x)); }
__device__ __forceinline__ float tanh_fast(float x) { return 1.0f - 2.0f / (__expf(2.0f * x) + 1.0f); }

// golden C->fragment b64 store index (bf16 units): quad g of a C tile goes to
// chunk (cb+(g>>1)), lane slot (n5 + 32*(g&1)), elements 4*hf..4*hf+3.
__device__ __forceinline__ int cwi(int cb, int g, int n5, int hf) {
  return (cb + (g >> 1)) * 512 + (n5 + 32 * (g & 1)) * 8 + 4 * hf;
}

__global__ __launch_bounds__(NT, 2)
void stgnn_kernel(const float* __restrict__ xh, const float* __restrict__ adj,
                  const float* __restrict__ Wenc, const float* __restrict__ benc,
                  const float* __restrict__ Wg1, const float* __restrict__ bg1,
                  const float* __restrict__ Wg2, const float* __restrict__ bg2,
                  const float* __restrict__ Wih, const float* __restrict__ Whh,
                  const float* __restrict__ bih, const float* __restrict__ bhh,
                  const float* __restrict__ Wd1, const float* __restrict__ bd1,
                  const float* __restrict__ Wd2, const float* __restrict__ bd2,
                  float* __restrict__ out) {
  __shared__ __align__(16) bf16 wcatTA[32768];  // Wcat^T A-frag (8 mt x 8 c)
  __shared__ __align__(16) bf16 wg1B[4096];     // Wg1 B-frag (2 nt x 4 c)
  __shared__ __align__(16) bf16 wg2B[4096];     // Wg2 B-frag
  __shared__ __align__(16) bf16 wencTA[1024];   // Wenc^T A-frag (2 mt x 1 c)
  __shared__ __align__(16) bf16 wd1TA[2048];    // Wd1^T A-frag (1 mt x 4 c)
  __shared__ __align__(16) bf16 wd2TA[1024];    // Wd2^T A-frag (1 mt x 2 c, d padded)
  __shared__ __align__(16) float sBenc[64];
  __shared__ __align__(16) float sBg1[64];
  __shared__ __align__(16) float sBg2[64];
  __shared__ __align__(16) float sBih[256];
  __shared__ __align__(16) float sBd1[32];
  __shared__ __align__(16) float sBd2[8];
  __shared__ float sDeg[32];
  __shared__ __align__(16) bf16 sXbA[8 * 512];   // per-wave x / [pred|stat] bf16, [node][f pad16]
  __shared__ __align__(16) bf16 sChA[8 * 2048];  // per-wave 4KB chain buffer

  const int tid = threadIdx.x;
  const int L   = tid & 63;
  const int w   = tid >> 6;
  const int n5  = L & 31;
  const int hf  = L >> 5;
  const long long b = (long long)blockIdx.x * 8 + w;

  bf16* sXb = sXbA + (w << 9);
  bf16* sCh = sChA + (w << 11);

  // ---------------- static staging ----------------
  for (int i = tid; i < 1024; i += NT) {
    int f = i >> 6, h = i & 63;
    float v = (f < 11) ? Wenc[f * 64 + h] : 0.0f;
    wencTA[(h >> 5) * 512 + ((h & 31) + 32 * ((f >> 3) & 1)) * 8 + (f & 7)] = (bf16)v;
  }
  for (int i = tid; i < 4096; i += NT) {
    int k = i >> 6, n = i & 63;
    int off = (((n >> 5) * 4 + (k >> 4)) * 64 + (n & 31) + 32 * ((k >> 3) & 1)) * 8 + (k & 7);
    wg1B[off] = (bf16)Wg1[i];
    wg2B[off] = (bf16)Wg2[i];
  }
  for (int i = tid; i < 32768; i += NT) {
    int gc = i >> 7, k = i & 127;
    float v = (k < 64) ? Wih[gc * 64 + k] : Whh[gc * 64 + (k - 64)];
    wcatTA[((gc >> 5) * 8 + (k >> 4)) * 512 + ((gc & 31) + 32 * ((k >> 3) & 1)) * 8 + (k & 7)] = (bf16)v;
  }
  for (int i = tid; i < 2048; i += NT) {
    int k = i >> 5, n = i & 31;
    wd1TA[(k >> 4) * 512 + (n + 32 * ((k >> 3) & 1)) * 8 + (k & 7)] = (bf16)Wd1[k * 32 + n];
  }
  for (int i = tid; i < 1024; i += NT) {
    int k = i >> 5, d = i & 31;
    float v = (d < 6) ? Wd2[k * 6 + d] : 0.0f;
    wd2TA[(k >> 4) * 512 + (d + 32 * ((k >> 3) & 1)) * 8 + (k & 7)] = (bf16)v;
  }
  for (int i = tid; i < 64; i += NT) { sBenc[i] = benc[i]; sBg1[i] = bg1[i]; sBg2[i] = bg2[i]; }
  for (int i = tid; i < 256; i += NT) sBih[i] = bih[i] + bhh[i];
  for (int i = tid; i < 32; i += NT) sBd1[i] = bd1[i];
  if (tid < 8) sBd2[tid] = (tid < 6) ? bd2[tid] : 0.0f;
  if (tid < 32) {
    float s = 0.0f;
    for (int j = 0; j < 32; ++j) s += (j == tid) ? 1.0f : adj[tid * 32 + j];
    sDeg[tid] = 1.0f / sqrtf(fmaxf(s, 1.0f));
  }
  for (int i = L; i < 512; i += 64) sXb[i] = (bf16)0.0f;  // zero-pad f>=11 forever
  __syncthreads();
  float* AhatS = (float*)sChA;
  for (int i = tid; i < 1024; i += NT) {
    int ii = i >> 5, jj = i & 31;
    float v = (ii == jj) ? 1.0f : adj[i];
    AhatS[i] = sDeg[ii] * v * sDeg[jj];
  }
  __syncthreads();
  bf16x8 ahHi[2], ahLo[2];
  #pragma unroll
  for (int c = 0; c < 2; ++c)
    #pragma unroll
    for (int j = 0; j < 8; ++j) {
      int k = 16 * c + 8 * hf + j;
      float v = AhatS[n5 * 32 + k];
      bf16 hi = (bf16)v;
      ahHi[c][j] = hi;
      ahLo[c][j] = (bf16)(v - (float)hi);
    }
  __syncthreads();  // last barrier: chain buffers are per-wave from here on

  // persistent per-wave registers
  float cx[32];
  #pragma unroll
  for (int i = 0; i < 32; ++i) cx[i] = 0.0f;
  bf16x8 xfhB[8];
  #pragma unroll
  for (int t = 0; t < 8; ++t)
    #pragma unroll
    for (int j = 0; j < 8; ++j) xfhB[t][j] = (bf16)0.0f;
  float predr[4] = {0.f, 0.f, 0.f, 0.f};
  float xpre[6];
  #pragma unroll
  for (int t = 0; t < 6; ++t) {
    int i = L + (t << 6);
    xpre[t] = (i < 352) ? xh[b * (TSTEPS * 352) + i] : 0.0f;
  }

  for (int step = 0; step < TSTEPS + FUT; ++step) {
    const bool de = (step >= TSTEPS);
    // ---- staging (encoder): commit prefetched x, prefetch next ----
    if (!de) {
      #pragma unroll
      for (int t = 0; t < 6; ++t) {
        int i = L + (t << 6);
        if (i < 352) { int j = i / 11, f = i - j * 11; sXb[(j << 4) + f] = (bf16)xpre[t]; }
      }
      if (step + 1 < TSTEPS) {
        #pragma unroll
        for (int t = 0; t < 6; ++t) {
          int i = L + (t << 6);
          if (i < 352) xpre[t] = xh[b * (TSTEPS * 352) + (step + 1) * 352 + i];
        }
      }
    }
    // ---- enc^T = relu(Wenc^T @ x^T + benc): C rows=h, cols=node -> t1-A ----
    {
      bf16x8 xB = *reinterpret_cast<const bf16x8*>(&sXb[(n5 << 4) + (hf << 3)]);
      #pragma unroll
      for (int mt = 0; mt < 2; ++mt) {
        f32x16 c;
        #pragma unroll
        for (int i = 0; i < 16; ++i) c[i] = 0.0f;
        c = __builtin_amdgcn_mfma_f32_32x32x16_bf16(
              *reinterpret_cast<const bf16x8*>(&wencTA[mt * 512 + L * 8]), xB, c, 0, 0, 0);
        #pragma unroll
        for (int g = 0; g < 4; ++g) {
          float4 bb = *reinterpret_cast<const float4*>(&sBenc[32 * mt + 8 * g + 4 * hf]);
          bf16x4 o = { (bf16)fmaxf(c[4*g+0] + bb.x, 0.f), (bf16)fmaxf(c[4*g+1] + bb.y, 0.f),
                       (bf16)fmaxf(c[4*g+2] + bb.z, 0.f), (bf16)fmaxf(c[4*g+3] + bb.w, 0.f) };
          *reinterpret_cast<bf16x4*>(&sCh[cwi(2 * mt, g, n5, hf)]) = o;
        }
      }
    }
    bf16x8 rA[4];
    #pragma unroll
    for (int t = 0; t < 4; ++t) rA[t] = *reinterpret_cast<const bf16x8*>(&sCh[t * 512 + L * 8]);
    // ---- t1 = enc @ Wg1: C rows=node, cols=h1 -> s1^T-A ----
    {
      #pragma unroll
      for (int nt = 0; nt < 2; ++nt) {
        f32x16 c;
        #pragma unroll
        for (int i = 0; i < 16; ++i) c[i] = 0.0f;
        #pragma unroll
        for (int cc = 0; cc < 4; ++cc)
          c = __builtin_amdgcn_mfma_f32_32x32x16_bf16(rA[cc],
                *reinterpret_cast<const bf16x8*>(&wg1B[(nt * 4 + cc) * 512 + L * 8]), c, 0, 0, 0);
        #pragma unroll
        for (int g = 0; g < 4; ++g) {
          bf16x4 o = { (bf16)c[4*g+0], (bf16)c[4*g+1], (bf16)c[4*g+2], (bf16)c[4*g+3] };
          *reinterpret_cast<bf16x4*>(&sCh[cwi(2 * nt, g, n5, hf)]) = o;
        }
      }
    }
    #pragma unroll
    for (int t = 0; t < 4; ++t) rA[t] = *reinterpret_cast<const bf16x8*>(&sCh[t * 512 + L * 8]);
    // ---- s1^T = t1^T @ Ahat^T + bg1, relu: C rows=h1, cols=node -> t2-A ----
    {
      #pragma unroll
      for (int mt = 0; mt < 2; ++mt) {
        f32x16 c;
        #pragma unroll
        for (int i = 0; i < 16; ++i) c[i] = 0.0f;
        #pragma unroll
        for (int cc = 0; cc < 2; ++cc) {
          c = __builtin_amdgcn_mfma_f32_32x32x16_bf16(rA[mt * 2 + cc], ahHi[cc], c, 0, 0, 0);
          c = __builtin_amdgcn_mfma_f32_32x32x16_bf16(rA[mt * 2 + cc], ahLo[cc], c, 0, 0, 0);
        }
        #pragma unroll
        for (int g = 0; g < 4; ++g) {
          float4 bb = *reinterpret_cast<const float4*>(&sBg1[32 * mt + 8 * g + 4 * hf]);
          bf16x4 o = { (bf16)fmaxf(c[4*g+0] + bb.x, 0.f), (bf16)fmaxf(c[4*g+1] + bb.y, 0.f),
                       (bf16)fmaxf(c[4*g+2] + bb.z, 0.f), (bf16)fmaxf(c[4*g+3] + bb.w, 0.f) };
          *reinterpret_cast<bf16x4*>(&sCh[cwi(2 * mt, g, n5, hf)]) = o;
        }
      }
    }
    #pragma unroll
    for (int t = 0; t < 4; ++t) rA[t] = *reinterpret_cast<const bf16x8*>(&sCh[t * 512 + L * 8]);
    // ---- t2 = s1 @ Wg2: C rows=node, cols=h2 -> xf^T-A ----
    {
      #pragma unroll
      for (int nt = 0; nt < 2; ++nt) {
        f32x16 c;
        #pragma unroll
        for (int i = 0; i < 16; ++i) c[i] = 0.0f;
        #pragma unroll
        for (int cc = 0; cc < 4; ++cc)
          c = __builtin_amdgcn_mfma_f32_32x32x16_bf16(rA[cc],
                *reinterpret_cast<const bf16x8*>(&wg2B[(nt * 4 + cc) * 512 + L * 8]), c, 0, 0, 0);
        #pragma unroll
        for (int g = 0; g < 4; ++g) {
          bf16x4 o = { (bf16)c[4*g+0], (bf16)c[4*g+1], (bf16)c[4*g+2], (bf16)c[4*g+3] };
          *reinterpret_cast<bf16x4*>(&sCh[cwi(2 * nt, g, n5, hf)]) = o;
        }
      }
    }
    #pragma unroll
    for (int t = 0; t < 4; ++t) rA[t] = *reinterpret_cast<const bf16x8*>(&sCh[t * 512 + L * 8]);
    // ---- xf^T = t2^T @ Ahat^T + bg2, relu: C rows=h2, cols=node -> xfh-B c0..3 ----
    {
      #pragma unroll
      for (int mt = 0; mt < 2; ++mt) {
        f32x16 c;
        #pragma unroll
        for (int i = 0; i < 16; ++i) c[i] = 0.0f;
        #pragma unroll
        for (int cc = 0; cc < 2; ++cc) {
          c = __builtin_amdgcn_mfma_f32_32x32x16_bf16(rA[mt * 2 + cc], ahHi[cc], c, 0, 0, 0);
          c = __builtin_amdgcn_mfma_f32_32x32x16_bf16(rA[mt * 2 + cc], ahLo[cc], c, 0, 0, 0);
        }
        #pragma unroll
        for (int g = 0; g < 4; ++g) {
          float4 bb = *reinterpret_cast<const float4*>(&sBg2[32 * mt + 8 * g + 4 * hf]);
          bf16x4 o = { (bf16)fmaxf(c[4*g+0] + bb.x, 0.f), (bf16)fmaxf(c[4*g+1] + bb.y, 0.f),
                       (bf16)fmaxf(c[4*g+2] + bb.z, 0.f), (bf16)fmaxf(c[4*g+3] + bb.w, 0.f) };
          *reinterpret_cast<bf16x4*>(&sCh[cwi(2 * mt, g, n5, hf)]) = o;
        }
      }
    }
    #pragma unroll
    for (int t = 0; t < 4; ++t) xfhB[t] = *reinterpret_cast<const bf16x8*>(&sCh[t * 512 + L * 8]);
    // ---- LSTM g^T = Wcat^T @ [xf|h]^T, two passes over h-halves ----
    #pragma unroll
    for (int p = 0; p < 2; ++p) {
      f32x16 ga[4];
      #pragma unroll
      for (int a = 0; a < 4; ++a)
        #pragma unroll
        for (int i = 0; i < 16; ++i) ga[a][i] = 0.0f;
      #pragma unroll
      for (int cc = 0; cc < 8; ++cc) {
        #pragma unroll
        for (int a = 0; a < 4; ++a)
          ga[a] = __builtin_amdgcn_mfma_f32_32x32x16_bf16(
                    *reinterpret_cast<const bf16x8*>(&wcatTA[((2 * a + p) * 8 + cc) * 512 + L * 8]),
                    xfhB[cc], ga[a], 0, 0, 0);
      }
      #pragma unroll
      for (int g = 0; g < 4; ++g) {
        float4 bI = *reinterpret_cast<const float4*>(&sBih[      32 * p + 8 * g + 4 * hf]);
        float4 bF = *reinterpret_cast<const float4*>(&sBih[ 64 + 32 * p + 8 * g + 4 * hf]);
        float4 bG = *reinterpret_cast<const float4*>(&sBih[128 + 32 * p + 8 * g + 4 * hf]);
        float4 bO = *reinterpret_cast<const float4*>(&sBih[192 + 32 * p + 8 * g + 4 * hf]);
        bf16 hq[4];
        #pragma unroll
        for (int i = 0; i < 4; ++i) {
          const int ri = 4 * g + i;
          float gi = ga[0][ri] + ((const float*)&bI)[i];
          float gf = ga[1][ri] + ((const float*)&bF)[i];
          float gg = ga[2][ri] + ((const float*)&bG)[i];
          float go = ga[3][ri] + ((const float*)&bO)[i];
          float ccv = sigm(gf) * cx[p * 16 + ri] + sigm(gi) * tanh_fast(gg);
          cx[p * 16 + ri] = ccv;
          hq[i] = (bf16)(sigm(go) * tanh_fast(ccv));
        }
        bf16x4 o = { hq[0], hq[1], hq[2], hq[3] };
        *reinterpret_cast<bf16x4*>(&sCh[cwi(2 * p, g, n5, hf)]) = o;
      }
    }
    #pragma unroll
    for (int t = 0; t < 4; ++t) xfhB[4 + t] = *reinterpret_cast<const bf16x8*>(&sCh[t * 512 + L * 8]);
    // ---- decoder: d1^T, d2^T, pred update (all wave-internal) ----
    if (de) {
      if (step == TSTEPS) {
        const float* px = xh + ((b * TSTEPS + (TSTEPS - 1)) * 32 + n5) * 11;
        if (hf == 0) { predr[0] = px[0]; predr[1] = px[1]; predr[2] = px[2]; predr[3] = px[3]; }
        else         { predr[0] = px[4]; predr[1] = px[5]; }
      }
      f32x16 cD;
      #pragma unroll
      for (int i = 0; i < 16; ++i) cD[i] = 0.0f;
      #pragma unroll
      for (int cc = 0; cc < 4; ++cc)
        cD = __builtin_amdgcn_mfma_f32_32x32x16_bf16(
               *reinterpret_cast<const bf16x8*>(&wd1TA[cc * 512 + L * 8]), xfhB[4 + cc], cD, 0, 0, 0);
      #pragma unroll
      for (int g = 0; g < 4; ++g) {
        float4 bb = *reinterpret_cast<const float4*>(&sBd1[8 * g + 4 * hf]);
        bf16x4 o = { (bf16)fmaxf(cD[4*g+0] + bb.x, 0.f), (bf16)fmaxf(cD[4*g+1] + bb.y, 0.f),
                     (bf16)fmaxf(cD[4*g+2] + bb.z, 0.f), (bf16)fmaxf(cD[4*g+3] + bb.w, 0.f) };
        *reinterpret_cast<bf16x4*>(&sCh[cwi(0, g, n5, hf)]) = o;
      }
      bf16x8 rB0 = *reinterpret_cast<const bf16x8*>(&sCh[L * 8]);
      bf16x8 rB1 = *reinterpret_cast<const bf16x8*>(&sCh[512 + L * 8]);
      f32x16 c2;
      #pragma unroll
      for (int i = 0; i < 16; ++i) c2[i] = 0.0f;
      c2 = __builtin_amdgcn_mfma_f32_32x32x16_bf16(
             *reinterpret_cast<const bf16x8*>(&wd2TA[L * 8]), rB0, c2, 0, 0, 0);
      c2 = __builtin_amdgcn_mfma_f32_32x32x16_bf16(
             *reinterpret_cast<const bf16x8*>(&wd2TA[512 + L * 8]), rB1, c2, 0, 0, 0);
      float* op = out + ((b * FUT + (step - TSTEPS)) * 32 + n5) * 6;
      if (hf == 0) {
        float p0 = predr[0] + c2[0] + sBd2[0];
        float p1 = predr[1] + c2[1] + sBd2[1];
        float p2 = predr[2] + c2[2] + sBd2[2];
        float p3 = predr[3] + c2[3] + sBd2[3];
        predr[0] = p0; predr[1] = p1; predr[2] = p2; predr[3] = p3;
        *reinterpret_cast<float2*>(op + 0) = make_float2(p0, p1);
        *reinterpret_cast<float2*>(op + 2) = make_float2(p2, p3);
        bf16x4 pb = { (bf16)p0, (bf16)p1, (bf16)p2, (bf16)p3 };
        *reinterpret_cast<bf16x4*>(&sXb[n5 << 4]) = pb;
      } else {
        float p4 = predr[0] + c2[0] + sBd2[4];
        float p5 = predr[1] + c2[1] + sBd2[5];
        predr[0] = p4; predr[1] = p5;
        *reinterpret_cast<float2*>(op + 4) = make_float2(p4, p5);
        sXb[(n5 << 4) + 4] = (bf16)p4;
        sXb[(n5 << 4) + 5] = (bf16)p5;
      }
    }
  }
}

extern "C" void kernel_launch(void* const* d_in, const int* in_sizes, int n_in,
                              void* d_out, int out_size, void* d_ws, size_t ws_size,
                              hipStream_t stream) {
  (void)in_sizes; (void)n_in; (void)d_ws; (void)ws_size; (void)out_size;
  const float* xh   = (const float*)d_in[0];
  const float* adj  = (const float*)d_in[1];
  const float* Wenc = (const float*)d_in[2];
  const float* benc = (const float*)d_in[3];
  const float* Wg1  = (const float*)d_in[4];
  const float* bg1  = (const float*)d_in[5];
  const float* Wg2  = (const float*)d_in[6];
  const float* bg2  = (const float*)d_in[7];
  const float* Wih  = (const float*)d_in[8];
  const float* Whh  = (const float*)d_in[9];
  const float* bih  = (const float*)d_in[10];
  const float* bhh  = (const float*)d_in[11];
  const float* Wd1  = (const float*)d_in[12];
  const float* bd1  = (const float*)d_in[13];
  const float* Wd2  = (const float*)d_in[14];
  const float* bd2  = (const float*)d_in[15];
  float* out = (float*)d_out;
  stgnn_kernel<<<dim3(256), dim3(NT), 0, stream>>>(
      xh, adj, Wenc, benc, Wg1, bg1, Wg2, bg2,
      Wih, Whh, bih, bhh, Wd1, bd1, Wd2, bd2, out);
}